// Round 2
// baseline (387.737 us; speedup 1.0000x reference)
//
#include <hip/hip_runtime.h>
#include <math.h>

#define B_    4
#define T_    8192
#define C_    1024
#define E_    64
#define NTOK  (B_*T_)          // 32768
#define KSEL  2

// d_out offsets (in floats): idx, scores, probs, importance, load
#define OFF_IDX    0
#define OFF_SCORES (NTOK*KSEL)               // 65536
#define OFF_PROBS  (2*NTOK*KSEL)             // 131072
#define OFF_IMP    (OFF_PROBS + NTOK*E_)     // 2228224
#define OFF_LOAD   (OFF_IMP + E_)            // 2228288

// workspace offsets (bytes)
#define WS_W64    0                          // 2048*64*8 = 1 MB (zeroed, fp64 atomically accumulated)
#define WS_W32    1048576                    // 1024*64*4 = 256 KB (refine, [d][e])
#define WS_WTH    1310720                    // 64*1024*2 = 128 KB bf16 hi, [e][k]
#define WS_WTL    1441792                    // 128 KB bf16 lo
#define WS_LB64   1572864                    // 4*64*8 = 2 KB
#define WS_LB32   1574912                    // 4*64*4 = 1 KB
#define WS_CNT    1575936                    // 4
#define WS_LIST   1576448                    // REFINE_CAP*4 = 32 KB

#define REFINE_CAP 8192
#define REFINE_EPS 3e-4f

typedef __attribute__((ext_vector_type(8))) short short8;
typedef __attribute__((ext_vector_type(4))) float f32x4;

// ---------------------------------------------------------------------------
// K1: w64[d][e] += sum_{c chunk} Wc[c][d] * Wg[e][c], d in 0..2047 (fp64).
// d<1024 -> Wcomb (x path); d>=1024 -> V (cond path).
// grid: 32 d-tiles (64 d each) x 8 c-chunks (128 c each) = 256 blocks.
// thread: e = tid&63, dg = tid>>6 -> 16 d's, acc[16] fp64, fp64 atomics out.
// ---------------------------------------------------------------------------
__global__ __launch_bounds__(256) void k_comb(const float* __restrict__ Wg,
                                              const float* __restrict__ Wc,
                                              double* __restrict__ w64) {
    __shared__ float wc_s[64 * 64];   // [c][d_local]
    __shared__ float wg_s[64 * 64];   // [c][e]  (transposed at stage time)
    const int tid   = threadIdx.x;
    const int e     = tid & 63;
    const int dg    = tid >> 6;                    // 0..3 (wave-uniform)
    const int dtile = (blockIdx.x & 31) * 64;
    const int cbase = (blockIdx.x >> 5) * 128;

    double acc[16];
#pragma unroll
    for (int i = 0; i < 16; ++i) acc[i] = 0.0;

    for (int cc = 0; cc < 128; cc += 64) {
        const int c0 = cbase + cc;
        __syncthreads();
        // stage Wc tile [64c][64d]: coalesced float4 rows
#pragma unroll
        for (int k = 0; k < 4; ++k) {
            int li = tid + k * 256;
            int r = li >> 4, c4 = (li & 15) * 4;
            *(float4*)&wc_s[r * 64 + c4] =
                *(const float4*)&Wc[(size_t)(c0 + r) * 2048 + dtile + c4];
        }
        // stage Wg rows coalesced, write transposed into wg_s[c][e]
#pragma unroll
        for (int k = 0; k < 4; ++k) {
            int li = tid + k * 256;
            int r = li >> 4, c4 = (li & 15) * 4;
            float4 v = *(const float4*)&Wg[(size_t)r * 1024 + c0 + c4];
            wg_s[(c4 + 0) * 64 + r] = v.x;
            wg_s[(c4 + 1) * 64 + r] = v.y;
            wg_s[(c4 + 2) * 64 + r] = v.z;
            wg_s[(c4 + 3) * 64 + r] = v.w;
        }
        __syncthreads();
        for (int c = 0; c < 64; ++c) {
            double wg = (double)wg_s[c * 64 + e];
            const float* wcrow = &wc_s[c * 64 + dg * 16];
#pragma unroll
            for (int i = 0; i < 16; ++i)
                acc[i] += wg * (double)wcrow[i];
        }
    }
#pragma unroll
    for (int i = 0; i < 16; ++i) {
        double* p = &w64[(size_t)(dtile + dg * 16 + i) * 64 + e];
#if __has_builtin(__builtin_amdgcn_global_atomic_fadd_f64)
        unsafeAtomicAdd(p, acc[i]);
#else
        atomicAdd(p, acc[i]);
#endif
    }
}

// ---------------------------------------------------------------------------
// K2: finalize: wcomb32[d][e], bf16 hi/lo split wTh/wTl [e][k]; lbias from V.
// blocks 0..63: per-expert split; blocks 64..67: lbias[b][e] (fp64).
// ---------------------------------------------------------------------------
__global__ __launch_bounds__(256) void k_finalize(const double* __restrict__ w64,
                                                  const float* __restrict__ cond,
                                                  float* __restrict__ wcomb32,
                                                  short* __restrict__ wTh,
                                                  short* __restrict__ wTl,
                                                  double* __restrict__ lbias64,
                                                  float* __restrict__ lbias32) {
    const int tid = threadIdx.x;
    if (blockIdx.x < 64) {
        const int e = blockIdx.x;
        for (int d = tid; d < 1024; d += 256) {
            float f = (float)w64[(size_t)d * 64 + e];
            wcomb32[d * 64 + e] = f;
            unsigned u = __float_as_uint(f);
            short hi = (short)(u >> 16);
            float r = f - __uint_as_float(u & 0xFFFF0000u);
            short lo = (short)(__float_as_uint(r) >> 16);
            wTh[e * 1024 + d] = hi;
            wTl[e * 1024 + d] = lo;
        }
    } else {
        const int b = blockIdx.x - 64;
        const int e = tid & 63, part = tid >> 6;
        double acc = 0.0;
        const int d0 = part * 256;
        for (int d = d0; d < d0 + 256; ++d)
            acc += (double)cond[b * 1024 + d] * w64[(size_t)(1024 + d) * 64 + e];
        __shared__ double red[256];
        red[tid] = acc;
        __syncthreads();
        if (tid < 64) {
            double s = red[tid] + red[tid + 64] + red[tid + 128] + red[tid + 192];
            lbias64[b * 64 + tid] = s;
            lbias32[b * 64 + tid] = (float)s;
        }
    }
}

// ---------------------------------------------------------------------------
// split a float into bf16 hi (truncate) + bf16 lo (residual, truncate)
// ---------------------------------------------------------------------------
__device__ __forceinline__ void cvt_split8(const float* __restrict__ p,
                                           short8& h, short8& l) {
    float4 v0 = *(const float4*)p;
    float4 v1 = *(const float4*)(p + 4);
    float xv[8] = {v0.x, v0.y, v0.z, v0.w, v1.x, v1.y, v1.z, v1.w};
#pragma unroll
    for (int j = 0; j < 8; ++j) {
        unsigned u = __float_as_uint(xv[j]);
        h[j] = (short)(u >> 16);
        float r = xv[j] - __uint_as_float(u & 0xFFFF0000u);
        l[j] = (short)(__float_as_uint(r) >> 16);
    }
}

// ---------------------------------------------------------------------------
// K_main: logits = x @ Wcomb + lbias[b] via bf16-split MFMA (no LDS in K-loop).
// 512 blocks x 256 threads; block = 64 tokens, wave = 16 tokens x 64 experts.
// A/B frag: [m|n = lane&15][k = (lane>>4)*8 + j]; C/D: col=lane&15,
// row=(lane>>4)*4+reg.
// ---------------------------------------------------------------------------
#define MT   64
#define XPAD 68

__global__ __launch_bounds__(256) void k_main(const float* __restrict__ x,
                                              const short* __restrict__ wTh,
                                              const short* __restrict__ wTl,
                                              const float* __restrict__ lbias32,
                                              float* __restrict__ out,
                                              unsigned int* __restrict__ ref_cnt,
                                              int* __restrict__ ref_list) {
    __shared__ float xs[MT * XPAD];     // logits tile; reused for exp tile
    __shared__ float invs[MT];
    __shared__ unsigned int cnts[E_];

    const int tid    = threadIdx.x;
    const int wid    = tid >> 6;
    const int lane   = tid & 63;
    const int nn     = lane & 15;       // A row (token) / B row (expert)
    const int q8     = (lane >> 4) * 8; // k offset within chunk
    const int token0 = blockIdx.x * MT;
    const int t0     = token0 + wid * 16;
    const int b      = token0 / T_;

    if (tid < E_) cnts[tid] = 0;

    f32x4 acc[4];
#pragma unroll
    for (int et = 0; et < 4; ++et) acc[et] = (f32x4){0.f, 0.f, 0.f, 0.f};

    const float* aptr = x + (size_t)(t0 + nn) * 1024 + q8;
#pragma unroll 2
    for (int k0 = 0; k0 < 1024; k0 += 32) {
        short8 ah, al;
        cvt_split8(aptr + k0, ah, al);
#pragma unroll
        for (int et = 0; et < 4; ++et) {
            const size_t boff = (size_t)(et * 16 + nn) * 1024 + k0 + q8;
            short8 bh = *(const short8*)(wTh + boff);
            short8 bl = *(const short8*)(wTl + boff);
            acc[et] = __builtin_amdgcn_mfma_f32_16x16x32_bf16(ah, bh, acc[et], 0, 0, 0);
            acc[et] = __builtin_amdgcn_mfma_f32_16x16x32_bf16(ah, bl, acc[et], 0, 0, 0);
            acc[et] = __builtin_amdgcn_mfma_f32_16x16x32_bf16(al, bh, acc[et], 0, 0, 0);
        }
    }

    // write logits (+ lbias) to LDS tile: token = wid*16 + (lane>>4)*4 + r,
    // expert = et*16 + nn
    const int q4 = (lane >> 4) * 4;
#pragma unroll
    for (int et = 0; et < 4; ++et) {
        float lb = lbias32[b * 64 + et * 16 + nn];
#pragma unroll
        for (int r = 0; r < 4; ++r) {
            int tok = wid * 16 + q4 + r;
            xs[tok * XPAD + et * 16 + nn] = acc[et][r] + lb;
        }
    }
    __syncthreads();

    if (tid < MT) {
        const int t = tid;
        float v1 = -1e30f, v2 = -1e30f, v3 = -1e30f;
        int i1 = 0, i2 = 0;
        for (int e = 0; e < E_; ++e) {
            float l = xs[t * XPAD + e];
            if (l > v1)      { v3 = v2; v2 = v1; i2 = i1; v1 = l; i1 = e; }
            else if (l > v2) { v3 = v2; v2 = l; i2 = e; }
            else if (l > v3) { v3 = l; }
        }
        float sum = 0.f;
        for (int e = 0; e < E_; ++e) {
            float ex = __expf(xs[t * XPAD + e] - v1);
            xs[t * XPAD + e] = ex;
            sum += ex;
        }
        invs[t] = 1.0f / sum;

        const int gt = token0 + t;
        float s1 = 1.0f / (1.0f + __expf(v2 - v1));   // softmax over top-2
        *(float2*)&out[OFF_IDX + (size_t)gt * 2]    = make_float2((float)i1, (float)i2);
        *(float2*)&out[OFF_SCORES + (size_t)gt * 2] = make_float2(s1, 1.0f - s1);
        atomicAdd(&cnts[i1], 1u);
        atomicAdd(&cnts[i2], 1u);

        float g12 = v1 - v2, g23 = v2 - v3;
        float g = g12 < g23 ? g12 : g23;
        if (g < REFINE_EPS) {
            unsigned int pos = atomicAdd(ref_cnt, 1u);
            if (pos < REFINE_CAP) ref_list[pos] = gt;
        }
    }
    __syncthreads();

    // probs: 4096 floats, coalesced float4
    float* probs = out + OFF_PROBS + (size_t)token0 * E_;
#pragma unroll
    for (int k = 0; k < 4; ++k) {
        int li4 = tid + k * 256;
        int tok = li4 >> 4;
        int c4 = (li4 & 15) << 2;
        float4 ex = *(const float4*)&xs[tok * XPAD + c4];
        float inv = invs[tok];
        *(float4*)&probs[(size_t)li4 * 4] =
            make_float4(ex.x * inv, ex.y * inv, ex.z * inv, ex.w * inv);
    }

    // importance + load: one atomic each per e per block
    if (tid < E_) {
        const int e = tid;
        float s = 0.f;
        for (int t = 0; t < MT; ++t) s += xs[t * XPAD + e] * invs[t];
        atomicAdd(&out[OFF_IMP + e],  s * (1.0f / (float)NTOK));
        atomicAdd(&out[OFF_LOAD + e], (float)cnts[e] * (1.0f / (float)(NTOK * KSEL)));
    }
}

// ---------------------------------------------------------------------------
// K_ref: fp64 re-evaluation of ambiguous tokens. One wave per flagged token,
// lane = expert, 4 split accumulators; wide grid (1024 waves).
// ---------------------------------------------------------------------------
__global__ __launch_bounds__(256) void k_refine(const float* __restrict__ x,
                                                const float* __restrict__ wcomb32,
                                                const double* __restrict__ lbias64,
                                                const unsigned int* __restrict__ ref_cnt,
                                                const int* __restrict__ ref_list,
                                                float* __restrict__ out) {
    int wave = (int)((blockIdx.x * blockDim.x + threadIdx.x) >> 6);
    int lane = threadIdx.x & 63;
    unsigned int n = *ref_cnt;
    if (n > REFINE_CAP) n = REFINE_CAP;
    const int nwaves = (int)((gridDim.x * blockDim.x) >> 6);

    for (unsigned int wi = wave; wi < n; wi += nwaves) {
        const int gt = ref_list[wi];
        const int b = gt / T_;
        const float* xrow = x + (size_t)gt * C_;
        double a0 = 0.0, a1 = 0.0, a2 = 0.0, a3 = 0.0;
        for (int d = 0; d < C_; d += 4) {
            a0 += (double)xrow[d + 0] * (double)wcomb32[(d + 0) * 64 + lane];
            a1 += (double)xrow[d + 1] * (double)wcomb32[(d + 1) * 64 + lane];
            a2 += (double)xrow[d + 2] * (double)wcomb32[(d + 2) * 64 + lane];
            a3 += (double)xrow[d + 3] * (double)wcomb32[(d + 3) * 64 + lane];
        }
        double acc = ((a0 + a1) + (a2 + a3)) + lbias64[b * 64 + lane];

        // top-1 (tie -> lower index)
        double v = acc; int id = lane;
        for (int off = 32; off > 0; off >>= 1) {
            double ov = __shfl_xor(v, off, 64);
            int oid   = __shfl_xor(id, off, 64);
            if (ov > v || (ov == v && oid < id)) { v = ov; id = oid; }
        }
        double v1 = v; int i1 = id;
        // top-2
        v = (lane == i1) ? -1e300 : acc; id = lane;
        for (int off = 32; off > 0; off >>= 1) {
            double ov = __shfl_xor(v, off, 64);
            int oid   = __shfl_xor(id, off, 64);
            if (ov > v || (ov == v && oid < id)) { v = ov; id = oid; }
        }
        double v2 = v; int i2 = id;

        if (lane == 0) {
            float s1 = (float)(1.0 / (1.0 + exp(v2 - v1)));
            *(float2*)&out[OFF_IDX + (size_t)gt * 2]    = make_float2((float)i1, (float)i2);
            *(float2*)&out[OFF_SCORES + (size_t)gt * 2] = make_float2(s1, 1.0f - s1);
        }
    }
}

// ---------------------------------------------------------------------------
extern "C" void kernel_launch(void* const* d_in, const int* in_sizes, int n_in,
                              void* d_out, int out_size, void* d_ws, size_t ws_size,
                              hipStream_t stream) {
    const float* x    = (const float*)d_in[0];   // (4,8192,1024)
    const float* cond = (const float*)d_in[1];   // (4,1024)
    const float* Wg   = (const float*)d_in[2];   // (64,1024)
    const float* Wc   = (const float*)d_in[3];   // (1024,2048)
    float* out = (float*)d_out;
    char*  ws  = (char*)d_ws;

    double* w64     = (double*)(ws + WS_W64);
    float*  wcomb32 = (float*)(ws + WS_W32);
    short*  wTh     = (short*)(ws + WS_WTH);
    short*  wTl     = (short*)(ws + WS_WTL);
    double* lbias64 = (double*)(ws + WS_LB64);
    float*  lbias32 = (float*)(ws + WS_LB32);
    unsigned int* ref_cnt = (unsigned int*)(ws + WS_CNT);
    int*    ref_list = (int*)(ws + WS_LIST);

    hipMemsetAsync(w64, 0, 2048 * 64 * sizeof(double), stream);
    hipMemsetAsync(ref_cnt, 0, 4, stream);
    hipMemsetAsync(out + OFF_IMP, 0, 2 * E_ * sizeof(float), stream);

    k_comb<<<256, 256, 0, stream>>>(Wg, Wc, w64);
    k_finalize<<<68, 256, 0, stream>>>(w64, cond, wcomb32, wTh, wTl, lbias64, lbias32);
    k_main<<<NTOK / MT, 256, 0, stream>>>(x, wTh, wTl, lbias32, out, ref_cnt, ref_list);
    k_refine<<<256, 256, 0, stream>>>(x, wcomb32, lbias64, ref_cnt, ref_list, out);
}

// Round 3
// 370.008 us; speedup vs baseline: 1.0479x; 1.0479x over previous
//
#include <hip/hip_runtime.h>
#include <math.h>

#define B_    4
#define T_    8192
#define C_    1024
#define E_    64
#define NTOK  (B_*T_)          // 32768
#define KSEL  2

// d_out offsets (in floats): idx, scores, probs, importance, load
#define OFF_IDX    0
#define OFF_SCORES (NTOK*KSEL)               // 65536
#define OFF_PROBS  (2*NTOK*KSEL)             // 131072
#define OFF_IMP    (OFF_PROBS + NTOK*E_)     // 2228224
#define OFF_LOAD   (OFF_IMP + E_)            // 2228288

// workspace offsets (bytes)
#define WS_W64    0                          // 2048*64*8 = 1 MB (fp64 atomic accum)
#define WS_W32    1048576                    // 1024*64*4 = 256 KB ([d][e], refine)
#define WS_BSWH   1310720                    // 128 KB bf16 hi, MFMA-frag order
#define WS_BSWL   1441792                    // 128 KB bf16 lo
#define WS_LB64   1572864                    // 4*64*8 = 2 KB
#define WS_LB32   1574912                    // 4*64*4 = 1 KB
#define WS_CNT    1575936                    // 4
#define WS_LIST   1576448                    // REFINE_CAP*4 = 32 KB

#define REFINE_CAP 8192
#define REFINE_EPS 3e-4f

typedef __attribute__((ext_vector_type(8))) short short8;
typedef __attribute__((ext_vector_type(4))) float f32x4;

// ---------------------------------------------------------------------------
// K1: w64[d][e] += sum_{c chunk} Wc[c][d] * Wg[e][c], d in 0..2047 (fp64).
// d<1024 -> Wcomb (x path); d>=1024 -> V (cond path).
// grid: 32 d-tiles x 8 c-chunks = 256 blocks. Also zeroes ref_cnt/imp/load.
// ---------------------------------------------------------------------------
__global__ __launch_bounds__(256) void k_comb(const float* __restrict__ Wg,
                                              const float* __restrict__ Wc,
                                              double* __restrict__ w64,
                                              float* __restrict__ out,
                                              unsigned int* __restrict__ ref_cnt) {
    __shared__ float wc_s[64 * 64];   // [c][d_local]
    __shared__ float wg_s[64 * 64];   // [c][e]  (transposed at stage time)
    const int tid   = threadIdx.x;
    const int e     = tid & 63;
    const int dg    = tid >> 6;                    // 0..3 (wave-uniform)
    const int dtile = (blockIdx.x & 31) * 64;
    const int cbase = (blockIdx.x >> 5) * 128;

    if (blockIdx.x == 0) {                         // fold small zero-inits here
        if (tid < 2 * E_) out[OFF_IMP + tid] = 0.f;
        if (tid == 2 * E_) *ref_cnt = 0u;
    }

    double acc[16];
#pragma unroll
    for (int i = 0; i < 16; ++i) acc[i] = 0.0;

    for (int cc = 0; cc < 128; cc += 64) {
        const int c0 = cbase + cc;
        __syncthreads();
#pragma unroll
        for (int k = 0; k < 4; ++k) {
            int li = tid + k * 256;
            int r = li >> 4, c4 = (li & 15) * 4;
            *(float4*)&wc_s[r * 64 + c4] =
                *(const float4*)&Wc[(size_t)(c0 + r) * 2048 + dtile + c4];
        }
#pragma unroll
        for (int k = 0; k < 4; ++k) {
            int li = tid + k * 256;
            int r = li >> 4, c4 = (li & 15) * 4;
            float4 v = *(const float4*)&Wg[(size_t)r * 1024 + c0 + c4];
            wg_s[(c4 + 0) * 64 + r] = v.x;
            wg_s[(c4 + 1) * 64 + r] = v.y;
            wg_s[(c4 + 2) * 64 + r] = v.z;
            wg_s[(c4 + 3) * 64 + r] = v.w;
        }
        __syncthreads();
        for (int c = 0; c < 64; ++c) {
            double wg = (double)wg_s[c * 64 + e];
            const float* wcrow = &wc_s[c * 64 + dg * 16];
#pragma unroll
            for (int i = 0; i < 16; ++i)
                acc[i] += wg * (double)wcrow[i];
        }
    }
#pragma unroll
    for (int i = 0; i < 16; ++i) {
        double* p = &w64[(size_t)(dtile + dg * 16 + i) * 64 + e];
#if __has_builtin(__builtin_amdgcn_global_atomic_fadd_f64)
        unsafeAtomicAdd(p, acc[i]);
#else
        atomicAdd(p, acc[i]);
#endif
    }
}

// ---------------------------------------------------------------------------
// K2: finalize. blocks 0..63 (e=blk): wcomb32[d][e] + bf16 hi/lo split into
// MFMA-frag-swizzled bswH/bswL: slab s = kchunk*4 + et holds 512 shorts,
// element (lane=qsel*16+nn, j) at s*512 + lane*8 + j.
// blocks 64..67: lbias[b][e] (fp64) from V-half of w64.
// ---------------------------------------------------------------------------
__global__ __launch_bounds__(256) void k_finalize(const double* __restrict__ w64,
                                                  const float* __restrict__ cond,
                                                  float* __restrict__ wcomb32,
                                                  short* __restrict__ bswH,
                                                  short* __restrict__ bswL,
                                                  double* __restrict__ lbias64,
                                                  float* __restrict__ lbias32) {
    const int tid = threadIdx.x;
    if (blockIdx.x < 64) {
        const int e  = blockIdx.x;
        const int et = e >> 4, nn = e & 15;
        for (int d = tid; d < 1024; d += 256) {
            float f = (float)w64[(size_t)d * 64 + e];
            wcomb32[d * 64 + e] = f;
            unsigned u = __float_as_uint(f);
            short hi = (short)(u >> 16);
            float r = f - __uint_as_float(u & 0xFFFF0000u);
            short lo = (short)(__float_as_uint(r) >> 16);
            int kchunk = d >> 5, qsel = (d >> 3) & 3, j = d & 7;
            int idx = ((kchunk * 4 + et) * 64 + qsel * 16 + nn) * 8 + j;
            bswH[idx] = hi;
            bswL[idx] = lo;
        }
    } else {
        const int b = blockIdx.x - 64;
        const int e = tid & 63, part = tid >> 6;
        double acc = 0.0;
        const int d0 = part * 256;
        for (int d = d0; d < d0 + 256; ++d)
            acc += (double)cond[b * 1024 + d] * w64[(size_t)(1024 + d) * 64 + e];
        __shared__ double red[256];
        red[tid] = acc;
        __syncthreads();
        if (tid < 64) {
            double s = red[tid] + red[tid + 64] + red[tid + 128] + red[tid + 192];
            lbias64[b * 64 + tid] = s;
            lbias32[b * 64 + tid] = (float)s;
        }
    }
}

// ---------------------------------------------------------------------------
// split 8 consecutive floats into bf16 hi (truncate) + bf16 lo (residual)
// ---------------------------------------------------------------------------
__device__ __forceinline__ void cvt_split8(const float* __restrict__ p,
                                           short8& h, short8& l) {
    float4 v0 = *(const float4*)p;
    float4 v1 = *(const float4*)(p + 4);
    float xv[8] = {v0.x, v0.y, v0.z, v0.w, v1.x, v1.y, v1.z, v1.w};
#pragma unroll
    for (int j = 0; j < 8; ++j) {
        unsigned u = __float_as_uint(xv[j]);
        h[j] = (short)(u >> 16);
        float r = xv[j] - __uint_as_float(u & 0xFFFF0000u);
        l[j] = (short)(__float_as_uint(r) >> 16);
    }
}

// ---------------------------------------------------------------------------
// K_main: logits = x @ Wcomb + lbias[b], bf16-split MFMA, K-split x4 in-block.
// 1024 blocks x 256 thr; block = 32 tokens; wave w owns K range [w*256,+256).
// Wave tile: 32 tok (2 A-frags) x 64 exp (4 et). No LDS / barriers in K-loop.
// A/B frag: [m|n = lane&15][k = (lane>>4)*8 + j]; C/D: col=lane&15 (n),
// row=(lane>>4)*4+reg (m).
// ---------------------------------------------------------------------------
#define MT    32
#define ROWP  65          // accbuf row stride (pad: +1 breaks 64-stride banks)

__global__ __launch_bounds__(256, 4) void k_main(const float* __restrict__ x,
                                                 const short* __restrict__ bswH,
                                                 const short* __restrict__ bswL,
                                                 const float* __restrict__ lbias32,
                                                 float* __restrict__ out,
                                                 unsigned int* __restrict__ ref_cnt,
                                                 int* __restrict__ ref_list) {
    __shared__ float accbuf[4 * MT * ROWP];   // 33.3 KB: [w][tok][e] partials
    __shared__ float invs[MT];
    __shared__ unsigned int cnts[E_];

    const int tid    = threadIdx.x;
    const int wid    = tid >> 6;
    const int lane   = tid & 63;
    const int nn     = lane & 15;
    const int qsel   = lane >> 4;
    const int token0 = blockIdx.x * MT;
    const int b      = token0 >> 13;          // /8192

    if (tid < E_) cnts[tid] = 0;

    f32x4 acc[2][4];
#pragma unroll
    for (int m = 0; m < 2; ++m)
#pragma unroll
        for (int et = 0; et < 4; ++et) acc[m][et] = (f32x4){0.f, 0.f, 0.f, 0.f};

    // A pointers: this wave's K-quarter, lane's qsel sub-offset
    const float* a0 = x + (size_t)(token0 + nn) * 1024 + wid * 256 + qsel * 8;
    const float* a1 = a0 + (size_t)16 * 1024;
    // B slabs: kchunk = wid*8 + kc; slab = kchunk*4 + et; 512 shorts per slab
    const short* bh0 = bswH + ((size_t)(wid * 8) * 4) * 512 + lane * 8;
    const short* bl0 = bswL + ((size_t)(wid * 8) * 4) * 512 + lane * 8;

#pragma unroll 2
    for (int kc = 0; kc < 8; ++kc) {
        short8 ah0, al0, ah1, al1;
        cvt_split8(a0 + kc * 32, ah0, al0);
        cvt_split8(a1 + kc * 32, ah1, al1);
        const short* bh = bh0 + (size_t)kc * 4 * 512;
        const short* bl = bl0 + (size_t)kc * 4 * 512;
#pragma unroll
        for (int et = 0; et < 4; ++et) {
            short8 b_h = *(const short8*)(bh + et * 512);
            short8 b_l = *(const short8*)(bl + et * 512);
            acc[0][et] = __builtin_amdgcn_mfma_f32_16x16x32_bf16(ah0, b_h, acc[0][et], 0, 0, 0);
            acc[0][et] = __builtin_amdgcn_mfma_f32_16x16x32_bf16(ah0, b_l, acc[0][et], 0, 0, 0);
            acc[0][et] = __builtin_amdgcn_mfma_f32_16x16x32_bf16(al0, b_h, acc[0][et], 0, 0, 0);
            acc[1][et] = __builtin_amdgcn_mfma_f32_16x16x32_bf16(ah1, b_h, acc[1][et], 0, 0, 0);
            acc[1][et] = __builtin_amdgcn_mfma_f32_16x16x32_bf16(ah1, b_l, acc[1][et], 0, 0, 0);
            acc[1][et] = __builtin_amdgcn_mfma_f32_16x16x32_bf16(al1, b_h, acc[1][et], 0, 0, 0);
        }
    }

    // dump partial accs: tok = m*16 + qsel*4 + r, e = et*16 + nn
    const int q4 = qsel * 4;
#pragma unroll
    for (int m = 0; m < 2; ++m)
#pragma unroll
        for (int et = 0; et < 4; ++et)
#pragma unroll
            for (int r = 0; r < 4; ++r)
                accbuf[wid * (MT * ROWP) + (m * 16 + q4 + r) * ROWP + et * 16 + nn] =
                    acc[m][et][r];
    __syncthreads();

    // reduce K-quarters + lbias -> logits in accbuf[0] region
    for (int li = tid; li < MT * E_; li += 256) {
        int tok = li >> 6, e = li & 63;
        int o = tok * ROWP + e;
        float s = accbuf[o] + accbuf[MT * ROWP + o] + accbuf[2 * MT * ROWP + o] +
                  accbuf[3 * MT * ROWP + o] + lbias32[b * 64 + e];
        accbuf[o] = s;
    }
    __syncthreads();

    if (tid < MT) {
        const int t = tid;
        const int base = t * ROWP;
        float v1 = -1e30f, v2 = -1e30f, v3 = -1e30f;
        int i1 = 0, i2 = 0;
        for (int e = 0; e < E_; ++e) {
            float l = accbuf[base + e];
            if (l > v1)      { v3 = v2; v2 = v1; i2 = i1; v1 = l; i1 = e; }
            else if (l > v2) { v3 = v2; v2 = l; i2 = e; }
            else if (l > v3) { v3 = l; }
        }
        float sum = 0.f;
        for (int e = 0; e < E_; ++e) {
            float ex = __expf(accbuf[base + e] - v1);
            accbuf[base + e] = ex;
            sum += ex;
        }
        invs[t] = 1.0f / sum;

        const int gt = token0 + t;
        float s1 = 1.0f / (1.0f + __expf(v2 - v1));   // softmax over top-2
        *(float2*)&out[OFF_IDX + (size_t)gt * 2]    = make_float2((float)i1, (float)i2);
        *(float2*)&out[OFF_SCORES + (size_t)gt * 2] = make_float2(s1, 1.0f - s1);
        atomicAdd(&cnts[i1], 1u);
        atomicAdd(&cnts[i2], 1u);

        float g12 = v1 - v2, g23 = v2 - v3;
        float g = g12 < g23 ? g12 : g23;
        if (g < REFINE_EPS) {
            unsigned int pos = atomicAdd(ref_cnt, 1u);
            if (pos < REFINE_CAP) ref_list[pos] = gt;
        }
    }
    __syncthreads();

    // probs: 2048 floats, coalesced float4 stores
    float* probs = out + OFF_PROBS + (size_t)token0 * E_;
#pragma unroll
    for (int k = 0; k < 2; ++k) {
        int li4 = tid + k * 256;                 // float4 index 0..511
        int tok = li4 >> 4;
        int c4 = (li4 & 15) << 2;
        float inv = invs[tok];
        int o = tok * ROWP + c4;
        *(float4*)&probs[(size_t)li4 * 4] =
            make_float4(accbuf[o] * inv, accbuf[o + 1] * inv,
                        accbuf[o + 2] * inv, accbuf[o + 3] * inv);
    }

    // importance + load: one atomic each per e per block
    if (tid < E_) {
        const int e = tid;
        float s = 0.f;
        for (int t = 0; t < MT; ++t) s += accbuf[t * ROWP + e] * invs[t];
        atomicAdd(&out[OFF_IMP + e],  s * (1.0f / (float)NTOK));
        atomicAdd(&out[OFF_LOAD + e], (float)cnts[e] * (1.0f / (float)(NTOK * KSEL)));
    }
}

// ---------------------------------------------------------------------------
// K_ref: fp64 re-evaluation of ambiguous tokens. One wave per flagged token,
// lane = expert, 4 split accumulators.
// ---------------------------------------------------------------------------
__global__ __launch_bounds__(256) void k_refine(const float* __restrict__ x,
                                                const float* __restrict__ wcomb32,
                                                const double* __restrict__ lbias64,
                                                const unsigned int* __restrict__ ref_cnt,
                                                const int* __restrict__ ref_list,
                                                float* __restrict__ out) {
    int wave = (int)((blockIdx.x * blockDim.x + threadIdx.x) >> 6);
    int lane = threadIdx.x & 63;
    unsigned int n = *ref_cnt;
    if (n > REFINE_CAP) n = REFINE_CAP;
    const int nwaves = (int)((gridDim.x * blockDim.x) >> 6);

    for (unsigned int wi = wave; wi < n; wi += nwaves) {
        const int gt = ref_list[wi];
        const int b = gt / T_;
        const float* xrow = x + (size_t)gt * C_;
        double a0 = 0.0, a1 = 0.0, a2 = 0.0, a3 = 0.0;
        for (int d = 0; d < C_; d += 4) {
            a0 += (double)xrow[d + 0] * (double)wcomb32[(d + 0) * 64 + lane];
            a1 += (double)xrow[d + 1] * (double)wcomb32[(d + 1) * 64 + lane];
            a2 += (double)xrow[d + 2] * (double)wcomb32[(d + 2) * 64 + lane];
            a3 += (double)xrow[d + 3] * (double)wcomb32[(d + 3) * 64 + lane];
        }
        double acc = ((a0 + a1) + (a2 + a3)) + lbias64[b * 64 + lane];

        double v = acc; int id = lane;
        for (int off = 32; off > 0; off >>= 1) {
            double ov = __shfl_xor(v, off, 64);
            int oid   = __shfl_xor(id, off, 64);
            if (ov > v || (ov == v && oid < id)) { v = ov; id = oid; }
        }
        double v1 = v; int i1 = id;
        v = (lane == i1) ? -1e300 : acc; id = lane;
        for (int off = 32; off > 0; off >>= 1) {
            double ov = __shfl_xor(v, off, 64);
            int oid   = __shfl_xor(id, off, 64);
            if (ov > v || (ov == v && oid < id)) { v = ov; id = oid; }
        }
        double v2 = v; int i2 = id;

        if (lane == 0) {
            float s1 = (float)(1.0 / (1.0 + exp(v2 - v1)));
            *(float2*)&out[OFF_IDX + (size_t)gt * 2]    = make_float2((float)i1, (float)i2);
            *(float2*)&out[OFF_SCORES + (size_t)gt * 2] = make_float2(s1, 1.0f - s1);
        }
    }
}

// ---------------------------------------------------------------------------
extern "C" void kernel_launch(void* const* d_in, const int* in_sizes, int n_in,
                              void* d_out, int out_size, void* d_ws, size_t ws_size,
                              hipStream_t stream) {
    const float* x    = (const float*)d_in[0];   // (4,8192,1024)
    const float* cond = (const float*)d_in[1];   // (4,1024)
    const float* Wg   = (const float*)d_in[2];   // (64,1024)
    const float* Wc   = (const float*)d_in[3];   // (1024,2048)
    float* out = (float*)d_out;
    char*  ws  = (char*)d_ws;

    double* w64     = (double*)(ws + WS_W64);
    float*  wcomb32 = (float*)(ws + WS_W32);
    short*  bswH    = (short*)(ws + WS_BSWH);
    short*  bswL    = (short*)(ws + WS_BSWL);
    double* lbias64 = (double*)(ws + WS_LB64);
    float*  lbias32 = (float*)(ws + WS_LB32);
    unsigned int* ref_cnt = (unsigned int*)(ws + WS_CNT);
    int*    ref_list = (int*)(ws + WS_LIST);

    hipMemsetAsync(w64, 0, 2048 * 64 * sizeof(double), stream);

    k_comb<<<256, 256, 0, stream>>>(Wg, Wc, w64, out, ref_cnt);
    k_finalize<<<68, 256, 0, stream>>>(w64, cond, wcomb32, bswH, bswL, lbias64, lbias32);
    k_main<<<NTOK / MT, 256, 0, stream>>>(x, bswH, bswL, lbias32, out, ref_cnt, ref_list);
    k_refine<<<128, 256, 0, stream>>>(x, wcomb32, lbias64, ref_cnt, ref_list, out);
}